// Round 3
// baseline (742.673 us; speedup 1.0000x reference)
//
#include <hip/hip_runtime.h>
#include <hip/hip_bf16.h>

#define C3 768
#define PIX 4096
#define NB 8

// ---------------------------------------------------------------------------
// Generic tiled SGEMM:  Y[b, m, p] = sum_k W[m,k] * X[b, k, p] + bias[m]
// BM=BN=64, BK=16, 256 threads, 4x4 microtile per thread.
// X/Y base pointers are chunk-local; b = local batch index within chunk.
// ---------------------------------------------------------------------------
template <int BK>
__global__ __launch_bounds__(256) void sgemm_bias(
    const float* __restrict__ W,    // [M, K]
    const float* __restrict__ X,    // [cb, K, 4096]
    const float* __restrict__ bias, // [M]
    float* __restrict__ Y,          // [cb, M, 4096]
    int M, int K)
{
    constexpr int BM = 64, BN = 64;
    __shared__ float As[BK][BM + 1];
    __shared__ float Bs[BK][BN];

    const int tid = threadIdx.x;
    const int bm  = blockIdx.y * BM;
    const int n0  = blockIdx.x * BN;
    const int b   = n0 >> 12;
    const int p0  = n0 & 4095;

    const int a_m = tid >> 2;
    const int a_k = (tid & 3) * 4;
    const int b_k = tid >> 4;
    const int b_n = (tid & 15) * 4;

    const float* Arow = W + (size_t)(bm + a_m) * K + a_k;
    const float* Brow = X + ((size_t)b * K + b_k) * PIX + p0 + b_n;

    const int tm = (tid >> 4) * 4;
    const int tn = (tid & 15) * 4;

    float acc[4][4] = {};

    for (int k0 = 0; k0 < K; k0 += BK) {
        float4 av = *(const float4*)(Arow + k0);
        float4 bv = *(const float4*)(Brow + (size_t)k0 * PIX);
        __syncthreads();
        As[a_k + 0][a_m] = av.x;
        As[a_k + 1][a_m] = av.y;
        As[a_k + 2][a_m] = av.z;
        As[a_k + 3][a_m] = av.w;
        *(float4*)&Bs[b_k][b_n] = bv;
        __syncthreads();
#pragma unroll
        for (int k = 0; k < BK; ++k) {
            float a[4], bb[4];
#pragma unroll
            for (int i = 0; i < 4; ++i) a[i] = As[k][tm + i];
#pragma unroll
            for (int j = 0; j < 4; ++j) bb[j] = Bs[k][tn + j];
#pragma unroll
            for (int i = 0; i < 4; ++i)
#pragma unroll
                for (int j = 0; j < 4; ++j)
                    acc[i][j] = fmaf(a[i], bb[j], acc[i][j]);
        }
    }

#pragma unroll
    for (int i = 0; i < 4; ++i) {
        float bv = bias[bm + tm + i];
        float4 o = make_float4(acc[i][0] + bv, acc[i][1] + bv,
                               acc[i][2] + bv, acc[i][3] + bv);
        *(float4*)(Y + ((size_t)b * M + bm + tm + i) * PIX + p0 + tn) = o;
    }
}

// ---------------------------------------------------------------------------
// Fused depthwise 3x3 (pad 1) + 5x5 (pad 2): read qkv once, write both.
// ---------------------------------------------------------------------------
__global__ __launch_bounds__(256) void dw35_kernel(
    const float* __restrict__ qkv,
    const float* __restrict__ w3, const float* __restrict__ b3,
    const float* __restrict__ w5, const float* __restrict__ b5,
    float* __restrict__ t3, float* __restrict__ t5)
{
    const int c = blockIdx.y;
    const int b = blockIdx.z;
    const int p = blockIdx.x * 256 + threadIdx.x;
    const int h = p >> 6, w = p & 63;

    const float* src = qkv + ((size_t)b * C3 + c) * PIX;

    float k3[9], k5[25];
#pragma unroll
    for (int i = 0; i < 9; ++i)  k3[i] = w3[c * 9 + i];
#pragma unroll
    for (int i = 0; i < 25; ++i) k5[i] = w5[c * 25 + i];

    float acc3 = b3[c], acc5 = b5[c];
#pragma unroll
    for (int dy = -2; dy <= 2; ++dy) {
        const int hh = h + dy;
        const bool okY = ((unsigned)hh < 64u);
#pragma unroll
        for (int dx = -2; dx <= 2; ++dx) {
            const int ww = w + dx;
            float v = (okY && ((unsigned)ww < 64u)) ? src[hh * 64 + ww] : 0.f;
            acc5 = fmaf(k5[(dy + 2) * 5 + (dx + 2)], v, acc5);
            if (dy >= -1 && dy <= 1 && dx >= -1 && dx <= 1)
                acc3 = fmaf(k3[(dy + 1) * 3 + (dx + 1)], v, acc3);
        }
    }
    const size_t o = ((size_t)b * C3 + c) * PIX + p;
    t3[o] = acc3;
    t5[o] = acc5;
}

// ---------------------------------------------------------------------------
// Grouped 1x1 conv, 32 groups of 24->24 channels. Safe in-place.
// ---------------------------------------------------------------------------
__global__ __launch_bounds__(256) void pw_group_kernel(
    const float* in, const float* __restrict__ w,
    const float* __restrict__ bias, float* out)
{
    const int g = blockIdx.y;
    const int b = blockIdx.z;
    const int p = blockIdx.x * 256 + threadIdx.x;

    const float* src = in + ((size_t)b * C3 + g * 24) * PIX + p;
    float v[24];
#pragma unroll
    for (int ic = 0; ic < 24; ++ic) v[ic] = src[(size_t)ic * PIX];

    float* dst = out + ((size_t)b * C3 + g * 24) * PIX + p;
    const float* wg = w + g * 24 * 24;
#pragma unroll
    for (int co = 0; co < 24; ++co) {
        float acc = bias[g * 24 + co];
#pragma unroll
        for (int ic = 0; ic < 24; ++ic)
            acc = fmaf(wg[co * 24 + ic], v[ic], acc);
        dst[(size_t)co * PIX] = acc;
    }
}

// ---------------------------------------------------------------------------
// vk[b,hh][d(9)][e(8)] = sum_p v_aug[d,p] * relu(k[e,p])
// ---------------------------------------------------------------------------
__global__ __launch_bounds__(256) void vk_reduce_kernel(
    const float* __restrict__ qkv, const float* __restrict__ s3,
    const float* __restrict__ s5, float* __restrict__ vkout)
{
    const int hh = blockIdx.x;  // 0..95
    const int b  = blockIdx.y;
    const float* src = (hh < 32) ? qkv : ((hh < 64) ? s3 : s5);
    const int ch0 = (hh & 31) * 24;
    const float* base = src + ((size_t)b * C3 + ch0) * PIX;

    float acc[9][8] = {};
    for (int p = threadIdx.x; p < PIX; p += 256) {
        float kk[8], vv[8];
#pragma unroll
        for (int e = 0; e < 8; ++e) kk[e] = fmaxf(base[(8 + e) * PIX + p], 0.f);
#pragma unroll
        for (int d = 0; d < 8; ++d) vv[d] = base[(16 + d) * PIX + p];
#pragma unroll
        for (int d = 0; d < 8; ++d)
#pragma unroll
            for (int e = 0; e < 8; ++e)
                acc[d][e] = fmaf(vv[d], kk[e], acc[d][e]);
#pragma unroll
        for (int e = 0; e < 8; ++e) acc[8][e] += kk[e];
    }

#pragma unroll
    for (int i = 0; i < 9; ++i)
#pragma unroll
        for (int j = 0; j < 8; ++j) {
            float s = acc[i][j];
            for (int off = 32; off; off >>= 1) s += __shfl_down(s, off, 64);
            acc[i][j] = s;
        }

    __shared__ float red[4][72];
    const int wave = threadIdx.x >> 6, lane = threadIdx.x & 63;
    if (lane == 0) {
#pragma unroll
        for (int i = 0; i < 9; ++i)
#pragma unroll
            for (int j = 0; j < 8; ++j) red[wave][i * 8 + j] = acc[i][j];
    }
    __syncthreads();
    const int t = threadIdx.x;
    if (t < 72) {
        float s = red[0][t] + red[1][t] + red[2][t] + red[3][t];
        vkout[((size_t)b * 96 + hh) * 72 + t] = s;
    }
}

// ---------------------------------------------------------------------------
// att[b, hh*8+d, p] = (sum_e vk[d,e]*q[e,p]) / (sum_e vk[8,e]*q[e,p] + eps)
// ---------------------------------------------------------------------------
__global__ __launch_bounds__(256) void att_apply_kernel(
    const float* __restrict__ qkv, const float* __restrict__ s3,
    const float* __restrict__ s5, const float* __restrict__ vkin,
    float* __restrict__ att)
{
    const int hh = blockIdx.y;
    const int b  = blockIdx.z;
    const int p  = blockIdx.x * 256 + threadIdx.x;

    __shared__ float vk[72];
    if (threadIdx.x < 72)
        vk[threadIdx.x] = vkin[((size_t)b * 96 + hh) * 72 + threadIdx.x];
    __syncthreads();

    const float* src = (hh < 32) ? qkv : ((hh < 64) ? s3 : s5);
    const int ch0 = (hh & 31) * 24;
    const float* base = src + ((size_t)b * C3 + ch0) * PIX + p;

    float q[8];
#pragma unroll
    for (int e = 0; e < 8; ++e) q[e] = fmaxf(base[(size_t)e * PIX], 0.f);

    float den = 0.f;
#pragma unroll
    for (int e = 0; e < 8; ++e) den = fmaf(vk[64 + e], q[e], den);
    const float inv = 1.f / (den + 1e-15f);

    float* dst = att + ((size_t)b * C3 + hh * 8) * PIX + p;
#pragma unroll
    for (int d = 0; d < 8; ++d) {
        float num = 0.f;
#pragma unroll
        for (int e = 0; e < 8; ++e) num = fmaf(vk[d * 8 + e], q[e], num);
        dst[(size_t)d * PIX] = num * inv;
    }
}

// ---------------------------------------------------------------------------
extern "C" void kernel_launch(void* const* d_in, const int* in_sizes, int n_in,
                              void* d_out, int out_size, void* d_ws, size_t ws_size,
                              hipStream_t stream)
{
    const float* x      = (const float*)d_in[0];
    const float* qkv_w  = (const float*)d_in[1];
    const float* qkv_b  = (const float*)d_in[2];
    const float* dw3_w  = (const float*)d_in[3];
    const float* dw3_b  = (const float*)d_in[4];
    const float* pw3_w  = (const float*)d_in[5];
    const float* pw3_b  = (const float*)d_in[6];
    const float* dw5_w  = (const float*)d_in[7];
    const float* dw5_b  = (const float*)d_in[8];
    const float* pw5_w  = (const float*)d_in[9];
    const float* pw5_b  = (const float*)d_in[10];
    const float* proj_w = (const float*)d_in[11];
    const float* proj_b = (const float*)d_in[12];
    float* out = (float*)d_out;

    const size_t SZb = (size_t)C3 * PIX;          // floats per batch per buffer

    // Pick largest batch-chunk whose workspace fits: 4 activation buffers
    // (qkv, t3, t5, att) of cb*SZb floats each + vk (cb*96*72 floats).
    int cb = NB;
    while (cb > 1) {
        size_t need = (4 * (size_t)cb * SZb + (size_t)cb * 96 * 72) * sizeof(float);
        if (need <= ws_size) break;
        cb >>= 1;
    }

    float* qkv = (float*)d_ws;
    float* t3  = qkv + (size_t)cb * SZb;
    float* t5  = t3  + (size_t)cb * SZb;
    float* att = t5  + (size_t)cb * SZb;
    float* vkb = att + (size_t)cb * SZb;

    for (int b0 = 0; b0 < NB; b0 += cb) {
        const float* xb  = x   + (size_t)b0 * 256 * PIX;
        float*       ob  = out + (size_t)b0 * 256 * PIX;

        // 1. qkv = 1x1 conv (SGEMM M=768 K=256)
        sgemm_bias<16><<<dim3(cb * 64, 12), 256, 0, stream>>>(
            qkv_w, xb, qkv_b, qkv, C3, 256);

        // 2. fused depthwise 3x3 + 5x5
        dw35_kernel<<<dim3(16, C3, cb), 256, 0, stream>>>(
            qkv, dw3_w, dw3_b, dw5_w, dw5_b, t3, t5);

        // 3. grouped pointwise convs (in-place)
        pw_group_kernel<<<dim3(16, 32, cb), 256, 0, stream>>>(t3, pw3_w, pw3_b, t3);
        pw_group_kernel<<<dim3(16, 32, cb), 256, 0, stream>>>(t5, pw5_w, pw5_b, t5);

        // 4. vk reduction
        vk_reduce_kernel<<<dim3(96, cb), 256, 0, stream>>>(qkv, t3, t5, vkb);

        // 5. attention apply
        att_apply_kernel<<<dim3(16, 96, cb), 256, 0, stream>>>(qkv, t3, t5, vkb, att);

        // 6. proj (SGEMM M=256 K=768)
        sgemm_bias<16><<<dim3(cb * 64, 4), 256, 0, stream>>>(
            proj_w, att, proj_b, ob, 256, 768);
    }
}